// Round 8
// baseline (188.307 us; speedup 1.0000x reference)
//
#include <hip/hip_runtime.h>

// DynamicHead R8 = R7 + (a) s_setprio(1) around the MFMA cluster [T5], (b)
// stage-issue moved before the MFMAs [T3 ordering], (c) final layer fused into
// the epilogue (X2 + final_kernel deleted; out = dot(relu(x2), w2eff) computed
// from registers, shfl_xor 16-lane reduce + 2KB LDS cross-wave reduce).
// R7 counters: fused 105us, MfmaUtil 43%, kstep 1306 cyc vs 620 floor (convoy);
// non-fused overhead (pack + final + gaps) was ~60us of the 186 total.

typedef __attribute__((ext_vector_type(8))) _Float16 half8;
typedef __attribute__((ext_vector_type(4))) _Float16 half4;
typedef __attribute__((ext_vector_type(4))) float floatx4;

#define XPAD 264  // halves per LDS row: 256 + 8

__device__ __forceinline__ void gload16(const _Float16* g, _Float16* l){
  // async global->LDS, 16B/lane; LDS dest = wave-uniform base + lane*16
  __builtin_amdgcn_global_load_lds(
      (const __attribute__((address_space(1))) void*)g,
      (__attribute__((address_space(3))) void*)l, 16, 0, 0);
}

// Stage one 16KB kstep-block of packed W into an LDS slot (2 chunks/thread).
__device__ __forceinline__ void stage_b(const _Float16* wt, _Float16* slot,
                                        int w, int l){
  gload16(wt +        w * 512 + l * 8, slot +        w * 512);
  gload16(wt + 4096 + w * 512 + l * 8, slot + 4096 + w * 512);
}

__device__ __forceinline__ void make_basis(float t, float* p){
  p[0] = 1.f; p[1] = t; p[2] = t*t; p[3] = p[2]*t;
  const float knots[8] = {1.f/9.f, 2.f/9.f, 3.f/9.f, 4.f/9.f,
                          5.f/9.f, 6.f/9.f, 7.f/9.f, 8.f/9.f};
  #pragma unroll
  for (int j = 0; j < 8; ++j){
    float d = t - knots[j];
    d = fmaxf(d, 0.f);
    p[4+j] = d*d*d;
  }
}

// Pack W (12,256,256) fp32 -> f16 MFMA-B-frag order via LDS transpose.
// kappa = s*8+ko; destination block position t = ko*12 + s (ko-outer stream
// order so the layer kernel's B pointer advances linearly 8192 halves/kstep).
__global__ __launch_bounds__(256)
void pack_w_kernel(const float* __restrict__ W0, const float* __restrict__ W1,
                   _Float16* __restrict__ Wp0, _Float16* __restrict__ Wp1){
  __shared__ float wl[32 * 260];
  const int blk = blockIdx.x;
  const float* W = (blk < 96) ? W0 : W1;
  _Float16* Wp   = (blk < 96) ? Wp0 : Wp1;
  const int c    = (blk < 96) ? blk : blk - 96;   // kappa = s*8+ko
  const int tid  = threadIdx.x;
  const float* src = W + (size_t)c * 8192;        // 32 k-rows x 256 cols
  #pragma unroll
  for (int it = 0; it < 8; ++it){
    int idx = it * 256 + tid;          // float4 index 0..2047
    int r = idx >> 6, c4 = idx & 63;
    float4 v = *(const float4*)(src + (size_t)idx * 4);
    float* d = &wl[r * 260 + c4 * 4];
    d[0] = v.x; d[1] = v.y; d[2] = v.z; d[3] = v.w;
  }
  __syncthreads();
  const int tpos = (c & 7) * 12 + (c >> 3);       // ko*12 + s
  _Float16* dst = Wp + (size_t)tpos * 8192;
  #pragma unroll
  for (int w = 0; w < 4; ++w){
    int v = w * 256 + tid;             // 0..1023
    int n16 = v & 15, qq = (v >> 4) & 3, ntg = v >> 6;
    half8 o;
    #pragma unroll
    for (int j = 0; j < 8; ++j)
      o[j] = (_Float16)wl[(qq * 8 + j) * 260 + ntg * 16 + n16];
    *(half8*)(dst + (size_t)v * 8) = o;
  }
}

// 96-kstep GEMM pass, LDS ring (4 x 16KB) + register double buffer.
// Iter t: vmcnt(2) [loads of t+1 landed; t+2's in flight] -> barrier ->
// ds_reads of kstep t+1 into bn -> issue stage of t+3 -> setprio(1) ->
// MFMA kstep t from regs -> setprio(0) -> rotate. WAR-safe: slot (t+3)&3
// was last read at iter t-2, two collective barriers earlier.
// Slot/buffer indices compile-time static since 12 % 4 == 0.
// Caller pre-stages slots 0,1 + __syncthreads (drain). Prologue stages slot 2.
// Tail stages overrun <=48KiB into the next allocated ws region (never read).
__device__ __forceinline__ void gemm_kloop(const _Float16* Xl, _Float16* Bl,
                                           const float* bldsT,
                                           const _Float16* __restrict__ wp,
                                           unsigned xbase, int wm, int wn,
                                           int l16, int w, int l,
                                           floatx4 acc[4][4]){
  const unsigned bbase = (unsigned)(wn * 2048 + l * 8);   // halves within slot
  half8 xc[4], xn[4], bc[4], bn[4];
  // prologue: issue slot-2 stage, then load kstep-0 state from LDS/regs
  stage_b(wp + 2 * 8192, Bl + 2 * 8192, w, l);
  #pragma unroll
  for (int nt = 0; nt < 4; ++nt)
    bc[nt] = *(const half8*)(Bl + bbase + nt * 512);      // slot 0 = kstep 0
  #pragma unroll
  for (int mt = 0; mt < 4; ++mt)
    xc[mt] = *(const half8*)&Xl[xbase + mt * 16 * XPAD];
  floatx4 btc = *(const floatx4*)&bldsT[wm * 64 + l16 * 4]; // s = 0

  for (int ko = 0; ko < 8; ++ko){
    #pragma unroll
    for (int s = 0; s < 12; ++s){
      // loads of kstep t+1 must be retired; the 2 loads of t+2 stay in flight
      __asm__ __volatile__("s_waitcnt vmcnt(2)" ::: "memory");
      __builtin_amdgcn_sched_barrier(0);
      __builtin_amdgcn_s_barrier();   // all waves' t+1 loads landed
      __builtin_amdgcn_sched_barrier(0);

      // issue reads for kstep t+1 (retire under the MFMA block below)
      #pragma unroll
      for (int nt = 0; nt < 4; ++nt)
        bn[nt] = *(const half8*)(Bl + ((s + 1) & 3) * 8192 + bbase + nt * 512);
      const int sn = (s == 11) ? 0 : s + 1;
      floatx4 btn = *(const floatx4*)&bldsT[sn * 128 + wm * 64 + l16 * 4];
      if (s == 0){   // next ko's A-frags (needed 12 ksteps later)
        const int kon = (ko + 1) & 7;   // wraps at ko=7; result discarded
        #pragma unroll
        for (int mt = 0; mt < 4; ++mt)
          xn[mt] = *(const half8*)&Xl[xbase + kon * 32 + mt * 16 * XPAD];
      }
      // issue stage for kstep t+3 early (T3 ordering: loads fly under MFMA)
      stage_b(wp + (size_t)(ko * 12 + s + 3) * 8192,
              Bl + ((s + 3) & 3) * 8192, w, l);

      // kstep t: registers only — basis scale then 16 MFMA
      _Float16 bh[4];
      #pragma unroll
      for (int mt = 0; mt < 4; ++mt) bh[mt] = (_Float16)btc[mt];
      half8 az[4];
      #pragma unroll
      for (int mt = 0; mt < 4; ++mt) az[mt] = xc[mt] * bh[mt];
      __builtin_amdgcn_s_setprio(1);
      #pragma unroll
      for (int mt = 0; mt < 4; ++mt)
        #pragma unroll
        for (int nt = 0; nt < 4; ++nt)
          acc[mt][nt] = __builtin_amdgcn_mfma_f32_16x16x32_f16(
              az[mt], bc[nt], acc[mt][nt], 0, 0, 0);
      __builtin_amdgcn_s_setprio(0);

      // rotate double buffers (renamed away by unroll)
      #pragma unroll
      for (int nt = 0; nt < 4; ++nt) bc[nt] = bn[nt];
      btc = btn;
      if (s == 11){
        #pragma unroll
        for (int mt = 0; mt < 4; ++mt) xc[mt] = xn[mt];
      }
    }
  }
}

// acc[mt][nt] += sum_s bas_s[row] * bias[s, col]
__device__ __forceinline__ void add_bias(const float* blds, const float* __restrict__ bias,
                                         int wm, int wn, int q, int l16,
                                         floatx4 acc[4][4]){
  for (int s = 0; s < 12; ++s){
    float bl[4];
    #pragma unroll
    for (int nt = 0; nt < 4; ++nt)
      bl[nt] = bias[s * 256 + wn * 64 + nt * 16 + l16];
    floatx4 bs[4];
    #pragma unroll
    for (int mt = 0; mt < 4; ++mt)
      bs[mt] = *(const floatx4*)&blds[s * 128 + wm * 64 + mt * 16 + q * 4];
    #pragma unroll
    for (int mt = 0; mt < 4; ++mt)
      #pragma unroll
      for (int nt = 0; nt < 4; ++nt)
        #pragma unroll
        for (int r = 0; r < 4; ++r)
          acc[mt][nt][r] += bs[mt][r] * bl[nt];
  }
}

// relu + scatter acc into Xl as f16 (C/D layout: col=lane&15, row=(lane>>4)*4+r)
__device__ __forceinline__ void scatter_to_xl(_Float16* Xl, floatx4 acc[4][4],
                                              int wm, int wn, int q, int l16){
  #pragma unroll
  for (int mt = 0; mt < 4; ++mt)
    #pragma unroll
    for (int nt = 0; nt < 4; ++nt)
      #pragma unroll
      for (int r = 0; r < 4; ++r)
        Xl[(wm * 64 + mt * 16 + q * 4 + r) * XPAD + wn * 64 + nt * 16 + l16] =
            (_Float16)fmaxf(acc[mt][nt][r], 0.f);
}

// Fully fused: layers 1+2 as MFMA GEMMs + final (out dim 1) in the epilogue.
// 128 rows x 256 cols per block, 512 thr = 8 waves (2m x 4n). Grid 256, 1/CU.
// LDS: Xl 67.5K + Bl 64K + basis 12K + w2l 12K + red 2K = 159,840 B (<160K).
__global__ __launch_bounds__(512, 2)
void fused_all_kernel(const float* __restrict__ feat, const float* __restrict__ treat,
                      const _Float16* __restrict__ Wp0, const float* __restrict__ b0,
                      const _Float16* __restrict__ Wp1, const float* __restrict__ b1,
                      const float* __restrict__ W2, const float* __restrict__ b2,
                      float* __restrict__ out){
  __shared__ _Float16 Xl[128 * XPAD];   // 67,584 B
  __shared__ _Float16 Bl[4 * 8192];     // 65,536 B (B ring)
  __shared__ float blds[12 * 128];      // 6,144 B (epilogue layout)
  __shared__ float bldsT[12 * 128];     // 6,144 B (k-loop layout)
  __shared__ float w2l[12 * 256];       // 12,288 B (final-layer weights)
  __shared__ float redbuf[128 * 4];     // 2,048 B (cross-wave dot reduce)
  __shared__ float b2l[12];

  const int tid  = threadIdx.x;
  const int m0   = blockIdx.x * 128;
  const int lane = tid & 63;
  const int wid  = tid >> 6;
  const int wm   = wid >> 2;
  const int wn   = wid & 3;
  const int q    = lane >> 4;
  const int l16  = lane & 15;

  // issue layer-1 B t=0,1 first (latency hidden under feat staging)
  stage_b(Wp0,        Bl,        wid, lane);
  stage_b(Wp0 + 8192, Bl + 8192, wid, lane);

  // ---- stage features (128 x 256, f32 -> f16) into LDS ----
  #pragma unroll
  for (int it = 0; it < 16; ++it){
    int idx = it * 512 + tid;            // 8192 float4 chunks
    int m = idx >> 6, c = idx & 63;
    float4 v = *(const float4*)(feat + (size_t)(m0 + m) * 256 + c * 4);
    half4 h = { (_Float16)v.x, (_Float16)v.y, (_Float16)v.z, (_Float16)v.w };
    *(half4*)&Xl[m * XPAD + c * 4] = h;
  }
  // stage W2 (12x256 f32) + b2 into LDS for the fused final layer
  #pragma unroll
  for (int it = 0; it < 6; ++it)
    w2l[it * 512 + tid] = W2[it * 512 + tid];
  if (tid < 12) b2l[tid] = b2[tid];
  if (tid < 128){
    float t = treat[m0 + tid];
    float p[12]; make_basis(t, p);
    const int r   = tid;
    const int tmt = (r >> 4) & 3;
    const int tl  = r & 15;
    const int twm = r >> 6;
    #pragma unroll
    for (int s = 0; s < 12; ++s){
      blds [s * 128 + r] = p[s];
      bldsT[s * 128 + twm * 64 + tl * 4 + tmt] = p[s];
    }
  }
  __syncthreads();   // drains vmcnt(0): slots 0,1 landed

  const unsigned xbase = (unsigned)(wm * 64 + l16) * XPAD + q * 8;

  const floatx4 zero = {0.f, 0.f, 0.f, 0.f};
  floatx4 acc[4][4];
  #pragma unroll
  for (int mt = 0; mt < 4; ++mt)
    #pragma unroll
    for (int nt = 0; nt < 4; ++nt) acc[mt][nt] = zero;

  // ---- layer 1 ----
  gemm_kloop(Xl, Bl, bldsT, Wp0, xbase, wm, wn, l16, wid, lane, acc);
  add_bias(blds, b0, wm, wn, q, l16, acc);
  __syncthreads();                       // drains the tail pad-loads
  scatter_to_xl(Xl, acc, wm, wn, q, l16);
  // issue layer-2 B t=0,1 under the barrier + scatter shadow
  stage_b(Wp1,        Bl,        wid, lane);
  stage_b(Wp1 + 8192, Bl + 8192, wid, lane);
  __syncthreads();                       // Xl rewritten + slots 0,1 landed

  // ---- layer 2 ----
  #pragma unroll
  for (int mt = 0; mt < 4; ++mt)
    #pragma unroll
    for (int nt = 0; nt < 4; ++nt) acc[mt][nt] = zero;
  gemm_kloop(Xl, Bl, bldsT, Wp1, xbase, wm, wn, l16, wid, lane, acc);
  add_bias(blds, b1, wm, wn, q, l16, acc);

  // ---- fused final layer: out[row] = sum_col relu(x2)*w2eff + basis.b2 ----
  // relu in place
  #pragma unroll
  for (int mt = 0; mt < 4; ++mt)
    #pragma unroll
    for (int nt = 0; nt < 4; ++nt)
      #pragma unroll
      for (int r = 0; r < 4; ++r)
        acc[mt][nt][r] = fmaxf(acc[mt][nt][r], 0.f);
  // per-thread partial dot: this thread holds rows (mt,r), cols (nt)
  float outp[4][4];                      // [mt][r]
  #pragma unroll
  for (int mt = 0; mt < 4; ++mt)
    #pragma unroll
    for (int r = 0; r < 4; ++r) outp[mt][r] = 0.f;
  for (int s = 0; s < 12; ++s){
    float w2v[4];
    #pragma unroll
    for (int nt = 0; nt < 4; ++nt)
      w2v[nt] = w2l[s * 256 + wn * 64 + nt * 16 + l16];
    floatx4 bs[4];
    #pragma unroll
    for (int mt = 0; mt < 4; ++mt)
      bs[mt] = *(const floatx4*)&blds[s * 128 + wm * 64 + mt * 16 + q * 4];
    #pragma unroll
    for (int mt = 0; mt < 4; ++mt)
      #pragma unroll
      for (int r = 0; r < 4; ++r){
        float tmp = acc[mt][0][r] * w2v[0] + acc[mt][1][r] * w2v[1]
                  + acc[mt][2][r] * w2v[2] + acc[mt][3][r] * w2v[3];
        outp[mt][r] += bs[mt][r] * tmp;
      }
  }
  // reduce across the 16 l16-lanes of each q group
  #pragma unroll
  for (int mt = 0; mt < 4; ++mt)
    #pragma unroll
    for (int r = 0; r < 4; ++r){
      float v = outp[mt][r];
      v += __shfl_xor(v, 1, 64);
      v += __shfl_xor(v, 2, 64);
      v += __shfl_xor(v, 4, 64);
      v += __shfl_xor(v, 8, 64);
      outp[mt][r] = v;
    }
  if (l16 == 0){
    #pragma unroll
    for (int mt = 0; mt < 4; ++mt)
      #pragma unroll
      for (int r = 0; r < 4; ++r){
        int row = wm * 64 + mt * 16 + q * 4 + r;
        redbuf[row * 4 + wn] = outp[mt][r];
      }
  }
  __syncthreads();
  if (tid < 128){
    float v = redbuf[tid * 4 + 0] + redbuf[tid * 4 + 1]
            + redbuf[tid * 4 + 2] + redbuf[tid * 4 + 3];
    float bb = 0.f;
    #pragma unroll
    for (int s = 0; s < 12; ++s) bb += blds[s * 128 + tid] * b2l[s];
    out[m0 + tid] = v + bb;
  }
}

extern "C" void kernel_launch(void* const* d_in, const int* in_sizes, int n_in,
                              void* d_out, int out_size, void* d_ws, size_t ws_size,
                              hipStream_t stream){
  const float* treat = (const float*)d_in[0];
  const float* feat  = (const float*)d_in[1];
  const float* W0    = (const float*)d_in[2];
  const float* b0    = (const float*)d_in[3];
  const float* W1    = (const float*)d_in[4];
  const float* b1    = (const float*)d_in[5];
  const float* W2    = (const float*)d_in[6];
  const float* b2    = (const float*)d_in[7];

  char* ws = (char*)d_ws;
  _Float16* Wp0 = (_Float16*)(ws);                     // 1,572,864 B
  _Float16* Wp1 = (_Float16*)(ws + 1572864);           // 1,572,864 B (Wp0 overrun pad)
  // region past Wp1 stays allocated (was X2) — absorbs the <=48KiB tail overrun
  float* out = (float*)d_out;

  pack_w_kernel<<<192, 256, 0, stream>>>(W0, W1, Wp0, Wp1);
  fused_all_kernel<<<256, 512, 0, stream>>>(feat, treat, Wp0, b0, Wp1, b1,
                                            W2, b2, out);
}

// Round 11
// 176.447 us; speedup vs baseline: 1.0672x; 1.0672x over previous
//
#include <hip/hip_runtime.h>

// DynamicHead R9 = R7 k-loop (proven 105us, MfmaUtil 43%) + R8's final-layer
// fusion (proven: non-fused overhead 81us -> 25us, WRITE 16MB -> 128KB).
// R8 regression post-mortem: stacking setprio [T5] + stage-before-MFMA onto
// the k-loop cost 55% (1306 -> 2040 cyc/kstep, MfmaUtil 27%) — reverted both;
// the lockstep 2-wave/SIMD schedule does not tolerate them (cf. m190).
// [R10 resubmission — container-level infra failure; source held fixed]

typedef __attribute__((ext_vector_type(8))) _Float16 half8;
typedef __attribute__((ext_vector_type(4))) _Float16 half4;
typedef __attribute__((ext_vector_type(4))) float floatx4;

#define XPAD 264  // halves per LDS row: 256 + 8

__device__ __forceinline__ void gload16(const _Float16* g, _Float16* l){
  // async global->LDS, 16B/lane; LDS dest = wave-uniform base + lane*16
  __builtin_amdgcn_global_load_lds(
      (const __attribute__((address_space(1))) void*)g,
      (__attribute__((address_space(3))) void*)l, 16, 0, 0);
}

// Stage one 16KB kstep-block of packed W into an LDS slot (2 chunks/thread).
__device__ __forceinline__ void stage_b(const _Float16* wt, _Float16* slot,
                                        int w, int l){
  gload16(wt +        w * 512 + l * 8, slot +        w * 512);
  gload16(wt + 4096 + w * 512 + l * 8, slot + 4096 + w * 512);
}

__device__ __forceinline__ void make_basis(float t, float* p){
  p[0] = 1.f; p[1] = t; p[2] = t*t; p[3] = p[2]*t;
  const float knots[8] = {1.f/9.f, 2.f/9.f, 3.f/9.f, 4.f/9.f,
                          5.f/9.f, 6.f/9.f, 7.f/9.f, 8.f/9.f};
  #pragma unroll
  for (int j = 0; j < 8; ++j){
    float d = t - knots[j];
    d = fmaxf(d, 0.f);
    p[4+j] = d*d*d;
  }
}

// Pack W (12,256,256) fp32 -> f16 MFMA-B-frag order via LDS transpose.
// kappa = s*8+ko; destination block position t = ko*12 + s (ko-outer stream
// order so the layer kernel's B pointer advances linearly 8192 halves/kstep).
__global__ __launch_bounds__(256)
void pack_w_kernel(const float* __restrict__ W0, const float* __restrict__ W1,
                   _Float16* __restrict__ Wp0, _Float16* __restrict__ Wp1){
  __shared__ float wl[32 * 260];
  const int blk = blockIdx.x;
  const float* W = (blk < 96) ? W0 : W1;
  _Float16* Wp   = (blk < 96) ? Wp0 : Wp1;
  const int c    = (blk < 96) ? blk : blk - 96;   // kappa = s*8+ko
  const int tid  = threadIdx.x;
  const float* src = W + (size_t)c * 8192;        // 32 k-rows x 256 cols
  #pragma unroll
  for (int it = 0; it < 8; ++it){
    int idx = it * 256 + tid;          // float4 index 0..2047
    int r = idx >> 6, c4 = idx & 63;
    float4 v = *(const float4*)(src + (size_t)idx * 4);
    float* d = &wl[r * 260 + c4 * 4];
    d[0] = v.x; d[1] = v.y; d[2] = v.z; d[3] = v.w;
  }
  __syncthreads();
  const int tpos = (c & 7) * 12 + (c >> 3);       // ko*12 + s
  _Float16* dst = Wp + (size_t)tpos * 8192;
  #pragma unroll
  for (int w = 0; w < 4; ++w){
    int v = w * 256 + tid;             // 0..1023
    int n16 = v & 15, qq = (v >> 4) & 3, ntg = v >> 6;
    half8 o;
    #pragma unroll
    for (int j = 0; j < 8; ++j)
      o[j] = (_Float16)wl[(qq * 8 + j) * 260 + ntg * 16 + n16];
    *(half8*)(dst + (size_t)v * 8) = o;
  }
}

// 96-kstep GEMM pass, LDS ring (4 x 16KB) + register double buffer.
// [R7 structure — measured 105us/43% MfmaUtil; do not reorder without A/B]
// Iter t: vmcnt(2) [loads of t+1 landed; t+2's in flight] -> barrier ->
// issue ds_reads of kstep t+1 into bn -> MFMA kstep t from bc (regs only)
// -> rotate -> issue stage of t+3 (WAR-safe: slot (t+3)&3 last read at iter
// t-2, two collective barriers earlier). Indices static since 12 % 4 == 0.
// Caller pre-stages slots 0,1 + __syncthreads (drain). Prologue stages slot 2.
// Tail stages overrun <=48KiB into the next allocated ws region (never read).
__device__ __forceinline__ void gemm_kloop(const _Float16* Xl, _Float16* Bl,
                                           const float* bldsT,
                                           const _Float16* __restrict__ wp,
                                           unsigned xbase, int wm, int wn,
                                           int l16, int w, int l,
                                           floatx4 acc[4][4]){
  const unsigned bbase = (unsigned)(wn * 2048 + l * 8);   // halves within slot
  half8 xc[4], xn[4], bc[4], bn[4];
  // prologue: issue slot-2 stage, then load kstep-0 state from LDS/regs
  stage_b(wp + 2 * 8192, Bl + 2 * 8192, w, l);
  #pragma unroll
  for (int nt = 0; nt < 4; ++nt)
    bc[nt] = *(const half8*)(Bl + bbase + nt * 512);      // slot 0 = kstep 0
  #pragma unroll
  for (int mt = 0; mt < 4; ++mt)
    xc[mt] = *(const half8*)&Xl[xbase + mt * 16 * XPAD];
  floatx4 btc = *(const floatx4*)&bldsT[wm * 64 + l16 * 4]; // s = 0

  for (int ko = 0; ko < 8; ++ko){
    #pragma unroll
    for (int s = 0; s < 12; ++s){
      // loads of kstep t+1 must be retired; the 2 loads of t+2 stay in flight
      __asm__ __volatile__("s_waitcnt vmcnt(2)" ::: "memory");
      __builtin_amdgcn_sched_barrier(0);
      __builtin_amdgcn_s_barrier();   // all waves' t+1 loads landed
      __builtin_amdgcn_sched_barrier(0);

      // issue reads for kstep t+1 (retire under the MFMA block below)
      #pragma unroll
      for (int nt = 0; nt < 4; ++nt)
        bn[nt] = *(const half8*)(Bl + ((s + 1) & 3) * 8192 + bbase + nt * 512);
      const int sn = (s == 11) ? 0 : s + 1;
      floatx4 btn = *(const floatx4*)&bldsT[sn * 128 + wm * 64 + l16 * 4];
      if (s == 0){   // next ko's A-frags (needed 12 ksteps later)
        const int kon = (ko + 1) & 7;   // wraps at ko=7; result discarded
        #pragma unroll
        for (int mt = 0; mt < 4; ++mt)
          xn[mt] = *(const half8*)&Xl[xbase + kon * 32 + mt * 16 * XPAD];
      }

      // kstep t: registers only — basis scale then 16 MFMA
      _Float16 bh[4];
      #pragma unroll
      for (int mt = 0; mt < 4; ++mt) bh[mt] = (_Float16)btc[mt];
      half8 az[4];
      #pragma unroll
      for (int mt = 0; mt < 4; ++mt) az[mt] = xc[mt] * bh[mt];
      #pragma unroll
      for (int mt = 0; mt < 4; ++mt)
        #pragma unroll
        for (int nt = 0; nt < 4; ++nt)
          acc[mt][nt] = __builtin_amdgcn_mfma_f32_16x16x32_f16(
              az[mt], bc[nt], acc[mt][nt], 0, 0, 0);

      // rotate double buffers (renamed away by unroll)
      #pragma unroll
      for (int nt = 0; nt < 4; ++nt) bc[nt] = bn[nt];
      btc = btn;
      if (s == 11){
        #pragma unroll
        for (int mt = 0; mt < 4; ++mt) xc[mt] = xn[mt];
      }
      // issue stage for kstep t+3 under the MFMA shadow
      stage_b(wp + (size_t)(ko * 12 + s + 3) * 8192,
              Bl + ((s + 3) & 3) * 8192, w, l);
    }
  }
}

// acc[mt][nt] += sum_s bas_s[row] * bias[s, col]
__device__ __forceinline__ void add_bias(const float* blds, const float* __restrict__ bias,
                                         int wm, int wn, int q, int l16,
                                         floatx4 acc[4][4]){
  for (int s = 0; s < 12; ++s){
    float bl[4];
    #pragma unroll
    for (int nt = 0; nt < 4; ++nt)
      bl[nt] = bias[s * 256 + wn * 64 + nt * 16 + l16];
    floatx4 bs[4];
    #pragma unroll
    for (int mt = 0; mt < 4; ++mt)
      bs[mt] = *(const floatx4*)&blds[s * 128 + wm * 64 + mt * 16 + q * 4];
    #pragma unroll
    for (int mt = 0; mt < 4; ++mt)
      #pragma unroll
      for (int nt = 0; nt < 4; ++nt)
        #pragma unroll
        for (int r = 0; r < 4; ++r)
          acc[mt][nt][r] += bs[mt][r] * bl[nt];
  }
}

// relu + scatter acc into Xl as f16 (C/D layout: col=lane&15, row=(lane>>4)*4+r)
__device__ __forceinline__ void scatter_to_xl(_Float16* Xl, floatx4 acc[4][4],
                                              int wm, int wn, int q, int l16){
  #pragma unroll
  for (int mt = 0; mt < 4; ++mt)
    #pragma unroll
    for (int nt = 0; nt < 4; ++nt)
      #pragma unroll
      for (int r = 0; r < 4; ++r)
        Xl[(wm * 64 + mt * 16 + q * 4 + r) * XPAD + wn * 64 + nt * 16 + l16] =
            (_Float16)fmaxf(acc[mt][nt][r], 0.f);
}

// Fully fused: layers 1+2 as MFMA GEMMs + final (out dim 1) in the epilogue.
// 128 rows x 256 cols per block, 512 thr = 8 waves (2m x 4n). Grid 256, 1/CU.
// LDS: Xl 67.5K + Bl 64K + basis 12K + w2l 12K + red 2K = 159,840 B (<160K).
__global__ __launch_bounds__(512, 2)
void fused_all_kernel(const float* __restrict__ feat, const float* __restrict__ treat,
                      const _Float16* __restrict__ Wp0, const float* __restrict__ b0,
                      const _Float16* __restrict__ Wp1, const float* __restrict__ b1,
                      const float* __restrict__ W2, const float* __restrict__ b2,
                      float* __restrict__ out){
  __shared__ _Float16 Xl[128 * XPAD];   // 67,584 B
  __shared__ _Float16 Bl[4 * 8192];     // 65,536 B (B ring)
  __shared__ float blds[12 * 128];      // 6,144 B (epilogue layout)
  __shared__ float bldsT[12 * 128];     // 6,144 B (k-loop layout)
  __shared__ float w2l[12 * 256];       // 12,288 B (final-layer weights)
  __shared__ float redbuf[128 * 4];     // 2,048 B (cross-wave dot reduce)
  __shared__ float b2l[12];

  const int tid  = threadIdx.x;
  const int m0   = blockIdx.x * 128;
  const int lane = tid & 63;
  const int wid  = tid >> 6;
  const int wm   = wid >> 2;
  const int wn   = wid & 3;
  const int q    = lane >> 4;
  const int l16  = lane & 15;

  // issue layer-1 B t=0,1 first (latency hidden under feat staging)
  stage_b(Wp0,        Bl,        wid, lane);
  stage_b(Wp0 + 8192, Bl + 8192, wid, lane);

  // ---- stage features (128 x 256, f32 -> f16) into LDS ----
  #pragma unroll
  for (int it = 0; it < 16; ++it){
    int idx = it * 512 + tid;            // 8192 float4 chunks
    int m = idx >> 6, c = idx & 63;
    float4 v = *(const float4*)(feat + (size_t)(m0 + m) * 256 + c * 4);
    half4 h = { (_Float16)v.x, (_Float16)v.y, (_Float16)v.z, (_Float16)v.w };
    *(half4*)&Xl[m * XPAD + c * 4] = h;
  }
  // stage W2 (12x256 f32) + b2 into LDS for the fused final layer
  #pragma unroll
  for (int it = 0; it < 6; ++it)
    w2l[it * 512 + tid] = W2[it * 512 + tid];
  if (tid < 12) b2l[tid] = b2[tid];
  if (tid < 128){
    float t = treat[m0 + tid];
    float p[12]; make_basis(t, p);
    const int r   = tid;
    const int tmt = (r >> 4) & 3;
    const int tl  = r & 15;
    const int twm = r >> 6;
    #pragma unroll
    for (int s = 0; s < 12; ++s){
      blds [s * 128 + r] = p[s];
      bldsT[s * 128 + twm * 64 + tl * 4 + tmt] = p[s];
    }
  }
  __syncthreads();   // drains vmcnt(0): slots 0,1 landed

  const unsigned xbase = (unsigned)(wm * 64 + l16) * XPAD + q * 8;

  const floatx4 zero = {0.f, 0.f, 0.f, 0.f};
  floatx4 acc[4][4];
  #pragma unroll
  for (int mt = 0; mt < 4; ++mt)
    #pragma unroll
    for (int nt = 0; nt < 4; ++nt) acc[mt][nt] = zero;

  // ---- layer 1 ----
  gemm_kloop(Xl, Bl, bldsT, Wp0, xbase, wm, wn, l16, wid, lane, acc);
  add_bias(blds, b0, wm, wn, q, l16, acc);
  __syncthreads();                       // drains the tail pad-loads
  scatter_to_xl(Xl, acc, wm, wn, q, l16);
  // issue layer-2 B t=0,1 under the barrier + scatter shadow
  stage_b(Wp1,        Bl,        wid, lane);
  stage_b(Wp1 + 8192, Bl + 8192, wid, lane);
  __syncthreads();                       // Xl rewritten + slots 0,1 landed

  // ---- layer 2 ----
  #pragma unroll
  for (int mt = 0; mt < 4; ++mt)
    #pragma unroll
    for (int nt = 0; nt < 4; ++nt) acc[mt][nt] = zero;
  gemm_kloop(Xl, Bl, bldsT, Wp1, xbase, wm, wn, l16, wid, lane, acc);
  add_bias(blds, b1, wm, wn, q, l16, acc);

  // ---- fused final layer: out[row] = sum_col relu(x2)*w2eff + basis.b2 ----
  #pragma unroll
  for (int mt = 0; mt < 4; ++mt)
    #pragma unroll
    for (int nt = 0; nt < 4; ++nt)
      #pragma unroll
      for (int r = 0; r < 4; ++r)
        acc[mt][nt][r] = fmaxf(acc[mt][nt][r], 0.f);
  // per-thread partial dot: this thread holds rows (mt,r), cols (nt)
  float outp[4][4];                      // [mt][r]
  #pragma unroll
  for (int mt = 0; mt < 4; ++mt)
    #pragma unroll
    for (int r = 0; r < 4; ++r) outp[mt][r] = 0.f;
  for (int s = 0; s < 12; ++s){
    float w2v[4];
    #pragma unroll
    for (int nt = 0; nt < 4; ++nt)
      w2v[nt] = w2l[s * 256 + wn * 64 + nt * 16 + l16];
    floatx4 bs[4];
    #pragma unroll
    for (int mt = 0; mt < 4; ++mt)
      bs[mt] = *(const floatx4*)&blds[s * 128 + wm * 64 + mt * 16 + q * 4];
    #pragma unroll
    for (int mt = 0; mt < 4; ++mt)
      #pragma unroll
      for (int r = 0; r < 4; ++r){
        float tmp = acc[mt][0][r] * w2v[0] + acc[mt][1][r] * w2v[1]
                  + acc[mt][2][r] * w2v[2] + acc[mt][3][r] * w2v[3];
        outp[mt][r] += bs[mt][r] * tmp;
      }
  }
  // reduce across the 16 l16-lanes of each q group
  #pragma unroll
  for (int mt = 0; mt < 4; ++mt)
    #pragma unroll
    for (int r = 0; r < 4; ++r){
      float v = outp[mt][r];
      v += __shfl_xor(v, 1, 64);
      v += __shfl_xor(v, 2, 64);
      v += __shfl_xor(v, 4, 64);
      v += __shfl_xor(v, 8, 64);
      outp[mt][r] = v;
    }
  if (l16 == 0){
    #pragma unroll
    for (int mt = 0; mt < 4; ++mt)
      #pragma unroll
      for (int r = 0; r < 4; ++r){
        int row = wm * 64 + mt * 16 + q * 4 + r;
        redbuf[row * 4 + wn] = outp[mt][r];
      }
  }
  __syncthreads();
  if (tid < 128){
    float v = redbuf[tid * 4 + 0] + redbuf[tid * 4 + 1]
            + redbuf[tid * 4 + 2] + redbuf[tid * 4 + 3];
    float bb = 0.f;
    #pragma unroll
    for (int s = 0; s < 12; ++s) bb += blds[s * 128 + tid] * b2l[s];
    out[m0 + tid] = v + bb;
  }
}

extern "C" void kernel_launch(void* const* d_in, const int* in_sizes, int n_in,
                              void* d_out, int out_size, void* d_ws, size_t ws_size,
                              hipStream_t stream){
  const float* treat = (const float*)d_in[0];
  const float* feat  = (const float*)d_in[1];
  const float* W0    = (const float*)d_in[2];
  const float* b0    = (const float*)d_in[3];
  const float* W1    = (const float*)d_in[4];
  const float* b1    = (const float*)d_in[5];
  const float* W2    = (const float*)d_in[6];
  const float* b2    = (const float*)d_in[7];

  char* ws = (char*)d_ws;
  _Float16* Wp0 = (_Float16*)(ws);                     // 1,572,864 B
  _Float16* Wp1 = (_Float16*)(ws + 1572864);           // 1,572,864 B (Wp0 overrun pad)
  // region past Wp1 stays allocated — absorbs the <=48KiB tail overrun
  float* out = (float*)d_out;

  pack_w_kernel<<<192, 256, 0, stream>>>(W0, W1, Wp0, Wp1);
  fused_all_kernel<<<256, 512, 0, stream>>>(feat, treat, Wp0, b0, Wp1, b1,
                                            W2, b2, out);
}